// Round 8
// baseline (823.194 us; speedup 1.0000x reference)
//
#include <hip/hip_runtime.h>
#include <hip/hip_bf16.h>

// TasteNet fused MLP: z(N,64) -> h1(128) relu -> h2(128) relu -> b(12) ->
// clamp/taste/segment-sum epilogue with x(N,9) -> out(N,3) fp32.
//
// R18: weights-in-registers, 2-wave team split-by-features.
// Model (R10-R17 data): wall = 3125 cy/CU/tile >> static work (~1500).
// The gap is 64 dependent ds_read_b128->MFMA steps/tile at queue-inflated
// ~250 cy latency; 56 of those reads are LOOP-INVARIANT WEIGHTS. Fix:
//  - Team = 2 waves on one 32-row tile. Wave A owns h1/h2 features 0-63 and
//    L3 K-half 0-63; wave B owns 64-127 (+ x load, acc3 merge, epilogue).
//  - Each wave preloads ITS HALF of W1/W2/W3 as MFMA A-frags into pinned
//    AGPRs (112 regs) once; steady-state MFMA chains are register-only.
//  - h1 halves exchanged via LDS (frag layout is lane-identical: plain
//    b128 copy, no transpose). L3 partial acc exchanged via 2 KB buffer.
//  - z staged per-team in LDS via global_load_lds (A issues; R17-verified
//    pre-swizzle), both waves read the same 8 chunks.
//  - 2 barriers/tile: B1 after h1x write (also A's z-refill issue point),
//    B2 after acc3 partial write + A's vmcnt(0) (z(t+1) landed).
// Budget/wave: 152 pinned AGPR + ~100 arch <= 256 @ 2 waves/SIMD.
// Blocks 256 thr (2 teams), grid 512 -> 2 blocks/CU, 8 waves/CU unchanged.
// LDS 52768 B staged; runtime overlay 36864 B (z 16K | h1x 16K | a3x 4K).

typedef __bf16 bf16x8 __attribute__((ext_vector_type(8)));
typedef float  f32x16 __attribute__((ext_vector_type(16)));
typedef unsigned int uint2v __attribute__((ext_vector_type(2)));
typedef unsigned int uint4v __attribute__((ext_vector_type(4)));

#define MFMA32(a, b, c) __builtin_amdgcn_mfma_f32_32x32x16_bf16((a), (b), (c), 0, 0, 0)
#define PIN_AGPR(v) asm("" : "+a"(v))

// ---- staging layout (bf16 elt offsets), verified R2-R17 ----
#define SW3 0        // 12 rows x 128 elts (preload reads m=12..31 overrun into
                     // SW1; garbage lands in acc regs 8..15, never read)
#define SW1 1536     // 128 rows x 64 elts (128 B row, xor-swizzled 16B chunks)
#define SW2 9728     // 128 rows x 128 elts (256 B row, swizzled)
#define SB1 26112
#define SB2 26240
#define SB3 26368
#define SMEM_ELTS 26384            // 52768 B

// ---- runtime overlay (byte offsets; valid after preload barrier) ----
#define ZSL(team)  ((team) * 8192)            // [0, 16384)
#define H1X(team)  (16384 + (team) * 8192)    // [16384, 32768)
#define A3X(team)  (32768 + (team) * 2048)    // [32768, 36864)

#define NBLK 512
#define NTHR 256
#define NTILE 16384            // 524288 rows / 32
#define TSTRIDE (NBLK * 2)     // 1024 teams -> exactly 16 tiles each

typedef __attribute__((address_space(3))) unsigned int lds_u32;
typedef __attribute__((address_space(1))) const unsigned int glb_u32;

// async 16B/lane global->LDS: dest = uniform base + lane*16 (linear).
__device__ __forceinline__ void gll16(const float* g, const void* l) {
  __builtin_amdgcn_global_load_lds((glb_u32*)g, (lds_u32*)l, 16, 0, 0);
}

__device__ __forceinline__ unsigned pkbf(float lo, float hi) {
  unsigned short lb = __builtin_bit_cast(unsigned short, (__bf16)lo);
  unsigned short hb = __builtin_bit_cast(unsigned short, (__bf16)hi);
  return ((unsigned)hb << 16) | (unsigned)lb;
}

// 32x32 C-layout -> next-layer B-frag via one permlane32_swap per packed pair.
// Verified R1-R17 (absmax 5.9e-3).
template <int SUB>
__device__ __forceinline__ bf16x8 mk_bfrag(const f32x16 h) {
  constexpr int B = SUB * 8;
  unsigned p01 = pkbf(h[B + 0], h[B + 1]);
  unsigned p23 = pkbf(h[B + 2], h[B + 3]);
  unsigned p45 = pkbf(h[B + 4], h[B + 5]);
  unsigned p67 = pkbf(h[B + 6], h[B + 7]);
  unsigned d0, d1, d2, d3;
#if __has_builtin(__builtin_amdgcn_permlane32_swap)
  uint2v r1 = __builtin_amdgcn_permlane32_swap(p01, p45, false, false);
  uint2v r2 = __builtin_amdgcn_permlane32_swap(p23, p67, false, false);
  d0 = r1[0]; d2 = r1[1];
  d1 = r2[0]; d3 = r2[1];
#else
  int hi = (threadIdx.x >> 5) & 1;
  unsigned sp01 = (unsigned)__shfl_xor((int)p01, 32, 64);
  unsigned sp23 = (unsigned)__shfl_xor((int)p23, 32, 64);
  unsigned sp45 = (unsigned)__shfl_xor((int)p45, 32, 64);
  unsigned sp67 = (unsigned)__shfl_xor((int)p67, 32, 64);
  d0 = hi ? sp45 : p01;
  d2 = hi ? p45  : sp01;
  d1 = hi ? sp67 : p23;
  d3 = hi ? p67  : sp23;
#endif
  uint4v t; t[0] = d0; t[1] = d1; t[2] = d2; t[3] = d3;
  return __builtin_bit_cast(bf16x8, t);
}

// LDS b128 read at a runtime byte offset (+ compile-time immediate).
__device__ __forceinline__ bf16x8 ldw(const __bf16* sm, int vaddr, int imm) {
  return *(const bf16x8*)((const char*)sm + vaddr + imm);
}
__device__ __forceinline__ float4 ldz(const __bf16* sm, int vaddr) {
  return *(const float4*)((const char*)sm + vaddr);
}

// bias A-frag: A[m][0] = v on q=0 lanes; MFMA'd against ones-B (B[0][:]=1)
__device__ __forceinline__ bf16x8 biasA(__bf16 v) {
  bf16x8 f;
  #pragma unroll
  for (int i = 0; i < 8; ++i) f[i] = (__bf16)0.0f;
  f[0] = v;
  return f;
}

__global__ __launch_bounds__(256, 2)
void tastenet_kernel(const float* __restrict__ x, const float* __restrict__ z,
                     const float* __restrict__ W1, const float* __restrict__ b1,
                     const float* __restrict__ W2, const float* __restrict__ b2,
                     const float* __restrict__ W3, const float* __restrict__ b3,
                     float* __restrict__ out) {
  __shared__ __align__(16) __bf16 sm[SMEM_ELTS];
  const int tid = threadIdx.x;
  unsigned* smw = (unsigned*)sm;
  char* smb = (char*)sm;

  // ---- stage weights transposed + bf16, xor-swizzled 16B chunks ----
  for (int i = tid; i < 4096; i += NTHR) {          // W1 (64x128)
    int m = i & 127, k = (i >> 7) * 2;
    smw[SW1 / 2 + m * 32 + (((k >> 3) ^ (m & 7)) << 2) + ((k >> 1) & 3)] =
        pkbf(W1[k * 128 + m], W1[(k + 1) * 128 + m]);
  }
  for (int i = tid; i < 8192; i += NTHR) {          // W2 (128x128)
    int m = i & 127, k = (i >> 7) * 2;
    smw[SW2 / 2 + m * 64 + (((k >> 3) ^ (m & 7)) << 2) + ((k >> 1) & 3)] =
        pkbf(W2[k * 128 + m], W2[(k + 1) * 128 + m]);
  }
  for (int i = tid; i < 768; i += NTHR) {           // W3 (128x12)
    int kk = i / 12, m = i - kk * 12, k = kk * 2;
    smw[SW3 / 2 + m * 64 + (((k >> 3) ^ (m & 7)) << 2) + ((k >> 1) & 3)] =
        pkbf(W3[k * 12 + m], W3[(k + 1) * 12 + m]);
  }
  if (tid < 128) { sm[SB1 + tid] = (__bf16)b1[tid]; sm[SB2 + tid] = (__bf16)b2[tid]; }
  if (tid < 12)  sm[SB3 + tid] = (__bf16)b3[tid];
  __syncthreads();

  const int wave = tid >> 6;          // 0..3
  const int lane = tid & 63;
  const int q    = lane >> 5;
  const int n    = lane & 31;
  const int s8   = n & 7;
  const int eq   = q ^ (s8 & 1);
  const int sh   = s8 >> 1;
  const int half = wave & 1;          // 0 = wave A (feats 0-63), 1 = B (64-127)
  const int team = wave >> 1;         // 0..1 within block

  // swizzled A-frag addresses (transient, preload only)
  int aw1v[4], aw2v[4];
  #pragma unroll
  for (int j = 0; j < 4; ++j) {
    aw1v[j] = n * 128 + eq * 16 + 32 * (j ^ sh);   // W1: 128 B rows
    aw2v[j] = n * 256 + eq * 16 + 32 * (j ^ sh);   // W2/W3: 256 B rows
  }

  // ---- preload this wave's weight half as pinned A-frags ----
  bf16x8 w1f[8], w2f[16], w3f[4];
  #pragma unroll
  for (int b = 0; b < 2; ++b)
    #pragma unroll
    for (int kt = 0; kt < 4; ++kt) {
      w1f[b * 4 + kt] = ldw(sm, aw1v[kt] + (2 * half + b) * 4096, SW1 * 2);
      PIN_AGPR(w1f[b * 4 + kt]);
    }
  #pragma unroll
  for (int b = 0; b < 2; ++b)
    #pragma unroll
    for (int kt = 0; kt < 8; ++kt) {
      w2f[b * 8 + kt] =
          ldw(sm, aw2v[kt & 3] + (2 * half + b) * 8192 + 128 * (kt >> 2), SW2 * 2);
      PIN_AGPR(w2f[b * 8 + kt]);
    }
  #pragma unroll
  for (int kt = 0; kt < 4; ++kt) {
    w3f[kt] = ldw(sm, aw2v[kt] + 128 * half, SW3 * 2);
    PIN_AGPR(w3f[kt]);
  }

  bf16x8 ones;
  #pragma unroll
  for (int i = 0; i < 8; ++i) ones[i] = (__bf16)0.0f;
  if (q == 0) ones[0] = (__bf16)1.0f;
  PIN_AGPR(ones);

  bf16x8 ba1[2], ba2[2], ba3;
  #pragma unroll
  for (int b = 0; b < 2; ++b) {
    ba1[b] = biasA((q == 0) ? sm[SB1 + (2 * half + b) * 32 + n] : (__bf16)0.0f);
    ba2[b] = biasA((q == 0) ? sm[SB2 + (2 * half + b) * 32 + n] : (__bf16)0.0f);
    PIN_AGPR(ba1[b]); PIN_AGPR(ba2[b]);
  }
  // bias on B's L3 partial only (added exactly once per output)
  ba3 = biasA((half == 1 && q == 0 && n < 12) ? sm[SB3 + n] : (__bf16)0.0f);
  PIN_AGPR(ba3);

  f32x16 zeroC;
  #pragma unroll
  for (int i = 0; i < 16; ++i) zeroC[i] = 0.0f;
  PIN_AGPR(zeroC);

  __syncthreads();   // preload reads done -> staging region may be overwritten

  // ---- z slot addressing (R17-verified pre-swizzle) ----
  const char* slotp = smb + ZSL(team);
  const int lr = lane >> 4, lc = lane & 15;
  int gofs[8];                        // A's global source offsets
  #pragma unroll
  for (int i = 0; i < 8; ++i) {
    int r = 4 * i + lr;
    gofs[i] = r * 64 + ((lc ^ (r & 15)) << 2);
  }
  int zrd[8];                         // both waves' read offsets
  #pragma unroll
  for (int kt = 0; kt < 4; ++kt)
    #pragma unroll
    for (int s = 0; s < 2; ++s)
      zrd[2 * kt + s] =
          ZSL(team) + n * 256 + (((4 * kt + 2 * q + s) ^ (n & 15)) << 4);

  const int teamg = blockIdx.x * 2 + team;

  // prologue: A stages first z tile; barrier publishes it to the team
  if (!half) {
    const float* zb = z + (long)teamg * 2048;
    #pragma unroll
    for (int i = 0; i < 8; ++i) gll16(zb + gofs[i], slotp + (i << 10));
    asm volatile("s_waitcnt vmcnt(0)" ::: "memory");
  }
  __syncthreads();

  #pragma unroll 1
  for (int t = teamg; t < NTILE; t += TSTRIDE) {
    const long row = (long)t * 32 + n;

    // B: x loads early (covered by L1+L2 compute)
    float xv0 = 0.f, xv1 = 0.f, xv2 = 0.f, xv3 = 0.f, xv4 = 0.f;
    if (half) {
      const float* xr = x + row * 9;
      xv0 = xr[q * 4 + 0]; xv1 = xr[q * 4 + 1];
      xv2 = xr[q * 4 + 2]; xv3 = xr[q * 4 + 3];
      xv4 = xr[8];
    }

    // z tile: LDS -> bf16 B-frags (both waves, same data)
    bf16x8 bz[4];
    #pragma unroll
    for (int kt = 0; kt < 4; ++kt) {
      float4 a = ldz(sm, zrd[2 * kt]);
      float4 b = ldz(sm, zrd[2 * kt + 1]);
      bf16x8 f;
      f[0] = (__bf16)a.x; f[1] = (__bf16)a.y; f[2] = (__bf16)a.z; f[3] = (__bf16)a.w;
      f[4] = (__bf16)b.x; f[5] = (__bf16)b.y; f[6] = (__bf16)b.z; f[7] = (__bf16)b.w;
      bz[kt] = f;
    }

    // ---- layer 1 (register-only MFMA): this wave's 2 feature blocks ----
    f32x16 dA = MFMA32(ba1[0], ones, zeroC);
    f32x16 dB = MFMA32(ba1[1], ones, zeroC);
    PIN_AGPR(dA); PIN_AGPR(dB);
    #pragma unroll
    for (int kt = 0; kt < 4; ++kt) {
      dA = MFMA32(w1f[kt],     bz[kt], dA);
      dB = MFMA32(w1f[4 + kt], bz[kt], dB);
    }
    #pragma unroll
    for (int i = 0; i < 16; ++i) { dA[i] = fmaxf(dA[i], 0.0f); dB[i] = fmaxf(dB[i], 0.0f); }
    bf16x8 f0 = mk_bfrag<0>(dA), f1 = mk_bfrag<1>(dA);
    bf16x8 f2 = mk_bfrag<0>(dB), f3 = mk_bfrag<1>(dB);

    // publish own h1 half (frag layout lane-identical: plain copy)
    {
      char* hb = smb + H1X(team) + half * 4096 + lane * 16;
      *(bf16x8*)(hb + 0)    = f0;
      *(bf16x8*)(hb + 1024) = f1;
      *(bf16x8*)(hb + 2048) = f2;
      *(bf16x8*)(hb + 3072) = f3;
    }
    __syncthreads();                      // B1: h1 halves visible; z reads done

    // A: refill team z slot for t+1 (async; lands during L2/L3)
    if (!half && t + TSTRIDE < NTILE) {
      const float* zb = z + (long)(t + TSTRIDE) * 2048;
      #pragma unroll
      for (int i = 0; i < 8; ++i) gll16(zb + gofs[i], slotp + (i << 10));
    }

    // assemble full h1 B-frag set: own in regs, partner from LDS
    bf16x8 bf2[8];
    bf2[4 * half + 0] = f0; bf2[4 * half + 1] = f1;
    bf2[4 * half + 2] = f2; bf2[4 * half + 3] = f3;
    {
      const char* hr = smb + H1X(team) + (half ^ 1) * 4096 + lane * 16;
      bf2[4 * (half ^ 1) + 0] = *(const bf16x8*)(hr + 0);
      bf2[4 * (half ^ 1) + 1] = *(const bf16x8*)(hr + 1024);
      bf2[4 * (half ^ 1) + 2] = *(const bf16x8*)(hr + 2048);
      bf2[4 * (half ^ 1) + 3] = *(const bf16x8*)(hr + 3072);
    }

    // ---- layer 2 (register-only): this wave's 2 h2 blocks, K=128 ----
    f32x16 pA = MFMA32(ba2[0], ones, zeroC);
    f32x16 pB = MFMA32(ba2[1], ones, zeroC);
    PIN_AGPR(pA); PIN_AGPR(pB);
    #pragma unroll
    for (int kt = 0; kt < 8; ++kt) {
      pA = MFMA32(w2f[kt],     bf2[kt], pA);
      pB = MFMA32(w2f[8 + kt], bf2[kt], pB);
    }
    #pragma unroll
    for (int i = 0; i < 16; ++i) { pA[i] = fmaxf(pA[i], 0.0f); pB[i] = fmaxf(pB[i], 0.0f); }

    // ---- layer 3 partial (register-only): K = this wave's h2 half ----
    f32x16 a3 = MFMA32(ba3, ones, zeroC);
    PIN_AGPR(a3);
    a3 = MFMA32(w3f[0], mk_bfrag<0>(pA), a3);
    a3 = MFMA32(w3f[1], mk_bfrag<1>(pA), a3);
    a3 = MFMA32(w3f[2], mk_bfrag<0>(pB), a3);
    a3 = MFMA32(w3f[3], mk_bfrag<1>(pB), a3);

    // A: publish partial (regs 0..7 carry all real outputs), confirm z(t+1)
    if (!half) {
      float4 w0, w1v;
      w0.x = a3[0]; w0.y = a3[1]; w0.z = a3[2]; w0.w = a3[3];
      w1v.x = a3[4]; w1v.y = a3[5]; w1v.z = a3[6]; w1v.w = a3[7];
      *(float4*)(smb + A3X(team) + lane * 16) = w0;
      *(float4*)(smb + A3X(team) + 1024 + lane * 16) = w1v;
      asm volatile("s_waitcnt vmcnt(0)" ::: "memory");
    }
    __syncthreads();                      // B2: partial visible; z(t+1) landed

    // B: merge partials + epilogue (verified R1-R17 mapping)
    if (half) {
      float4 p0 = *(const float4*)(smb + A3X(team) + lane * 16);
      float4 p1 = *(const float4*)(smb + A3X(team) + 1024 + lane * 16);
      float t0 = a3[0] + p0.x, t1 = a3[1] + p0.y;
      float t2 = a3[2] + p0.z, t3 = a3[3] + p0.w;
      float t4 = a3[4] + p1.x, t5 = a3[5] + p1.y;
      float t6 = a3[6] + p1.z, t7 = a3[7] + p1.w;
      float o0 = 0.f, o1 = 0.f, o2 = 0.f, g1v = 0.f, g2v = 0.f;
      if (q == 0) {
        t0 = fminf(t0, 0.0f); t1 = fminf(t1, 0.0f);
        t2 = fminf(t2, 0.0f); t3 = fminf(t3, 0.0f);
        t4 = fminf(t4, 0.0f);                       // feat 8
        o0 = xv0 * t0 + xv1 * t1 + xv2 * t2 + t5;   // seg0 + I9
        o1 = xv3 * t3 + t6;                         // seg1 part + I10
        o2 = xv4 * t4 + t7;                         // seg2 part + I11
      } else {
        t0 = fminf(t0, 0.0f); t1 = fminf(t1, 0.0f); // feats 4,5
        t3 = fminf(t3, 0.0f);                       // feat 7 (feat 6 passes)
        g1v = xv0 * t0 + xv1 * t1;
        g2v = xv2 * t2 + xv3 * t3;
      }
      float a1v = __shfl_xor(g1v, 32, 64);
      float a2v = __shfl_xor(g2v, 32, 64);
      if (q == 0) {
        float* op = out + row * 3;
        op[0] = o0;
        op[1] = o1 + a1v;
        op[2] = o2 + a2v;
      }
    }
  }
}

extern "C" void kernel_launch(void* const* d_in, const int* in_sizes, int n_in,
                              void* d_out, int out_size, void* d_ws, size_t ws_size,
                              hipStream_t stream) {
  const float* x  = (const float*)d_in[0];
  const float* z  = (const float*)d_in[1];
  const float* W1 = (const float*)d_in[2];
  const float* b1 = (const float*)d_in[3];
  const float* W2 = (const float*)d_in[4];
  const float* b2 = (const float*)d_in[5];
  const float* W3 = (const float*)d_in[6];
  const float* b3 = (const float*)d_in[7];
  tastenet_kernel<<<dim3(NBLK), dim3(NTHR), 0, stream>>>(
      x, z, W1, b1, W2, b2, W3, b3, (float*)d_out);
}

// Round 12
// 236.100 us; speedup vs baseline: 3.4866x; 3.4866x over previous
//
#include <hip/hip_runtime.h>
#include <hip/hip_bf16.h>

// TasteNet fused MLP: z(N,64) -> h1(128) relu -> h2(128) relu -> b(12) ->
// clamp/taste/segment-sum epilogue with x(N,9) -> out(N,3) fp32.
//
// R22 = R19/R20/R21 resubmitted verbatim (three consecutive
// GPUAcquisitionTimeout broker failures — this design has never run).
// Also the revert of R18's 695us regression. Theory unchanged:
// R19 = R10 VERBATIM (best measured: 83.4 us/dispatch, harness 235 us)
// + s_setprio(1/0) around the MFMA chain clusters (T5), zero register cost.
// R18's weights-in-AGPR attack spilled catastrophically (FETCH 410 MB,
// 695 us): 4th failure of the register-budget wall. R10 is a sharp local
// optimum; the only zero-pressure lever left is issue arbitration: R10's
// loop has no barriers, so the 2 waves/SIMD drift out of phase (one in
// MFMA chain, one in VALU pack) -> setprio(1) during MFMA-dense regions
// lets the MFMA wave win issue contention (T5's +4-7% regime, m191),
// setprio(0) during VALU phases yields back.
// Everything else identical to R10: z-prefetch ring in regs, AGPR-pinned
// biases/zeroC, grid 512 x (256,2), 2-wave/SIMD occupancy.

typedef __bf16 bf16x8 __attribute__((ext_vector_type(8)));
typedef float  f32x16 __attribute__((ext_vector_type(16)));
typedef unsigned int uint2v __attribute__((ext_vector_type(2)));
typedef unsigned int uint4v __attribute__((ext_vector_type(4)));

#define MFMA32(a, b, c) __builtin_amdgcn_mfma_f32_32x32x16_bf16((a), (b), (c), 0, 0, 0)
// Pin a value into the AGPR half of the unified file (R8 win).
#define PIN_AGPR(v) asm("" : "+a"(v))

// ---- LDS layout (bf16 element offsets), verified R2-R18 ----
#define SW3 0        // 12 rows x 128 elts (row reads m=12..31 overrun into SW1;
                     // garbage feats land in acc3 regs never read)
#define SW1 1536     // 128 rows x 64 elts (128 B row, xor-swizzled 16B chunks)
#define SW2 9728     // 128 rows x 128 elts (256 B row, swizzled)
#define SB1 26112
#define SB2 26240
#define SB3 26368
#define SMEM_ELTS 26384   // 52768 B

#define NBLK    512
#define NTILE   16384          // 524288 rows / 32
#define WSTRIDE (NBLK * 4)     // 2048 waves -> exactly 8 tiles each

__device__ __forceinline__ unsigned pkbf(float lo, float hi) {
  unsigned short lb = __builtin_bit_cast(unsigned short, (__bf16)lo);
  unsigned short hb = __builtin_bit_cast(unsigned short, (__bf16)hi);
  return ((unsigned)hb << 16) | (unsigned)lb;
}

// 32x32 C-layout -> next-layer B-frag via one permlane32_swap per packed pair.
// Verified R1-R18 (absmax 5.9e-3).
template <int SUB>
__device__ __forceinline__ bf16x8 mk_bfrag(const f32x16 h) {
  constexpr int B = SUB * 8;
  unsigned p01 = pkbf(h[B + 0], h[B + 1]);
  unsigned p23 = pkbf(h[B + 2], h[B + 3]);
  unsigned p45 = pkbf(h[B + 4], h[B + 5]);
  unsigned p67 = pkbf(h[B + 6], h[B + 7]);
  unsigned d0, d1, d2, d3;
#if __has_builtin(__builtin_amdgcn_permlane32_swap)
  uint2v r1 = __builtin_amdgcn_permlane32_swap(p01, p45, false, false);
  uint2v r2 = __builtin_amdgcn_permlane32_swap(p23, p67, false, false);
  d0 = r1[0]; d2 = r1[1];
  d1 = r2[0]; d3 = r2[1];
#else
  int hi = (threadIdx.x >> 5) & 1;
  unsigned sp01 = (unsigned)__shfl_xor((int)p01, 32, 64);
  unsigned sp23 = (unsigned)__shfl_xor((int)p23, 32, 64);
  unsigned sp45 = (unsigned)__shfl_xor((int)p45, 32, 64);
  unsigned sp67 = (unsigned)__shfl_xor((int)p67, 32, 64);
  d0 = hi ? sp45 : p01;
  d2 = hi ? p45  : sp01;
  d1 = hi ? sp67 : p23;
  d3 = hi ? p67  : sp23;
#endif
  uint4v t; t[0] = d0; t[1] = d1; t[2] = d2; t[3] = d3;
  return __builtin_bit_cast(bf16x8, t);
}

// LDS A-frag read: VGPR addr + compile-time immediate byte offset.
__device__ __forceinline__ bf16x8 ldw(const __bf16* sm, int vaddr, int imm) {
  return *(const bf16x8*)((const char*)sm + vaddr + imm);
}

// bias A-frag: A[m][0] = v on q=0 lanes; MFMA'd against ones-B (B[0][:]=1)
__device__ __forceinline__ bf16x8 biasA(__bf16 v) {
  bf16x8 f;
  #pragma unroll
  for (int i = 0; i < 8; ++i) f[i] = (__bf16)0.0f;
  f[0] = v;
  return f;
}

__global__ __launch_bounds__(256, 2)
void tastenet_kernel(const float* __restrict__ x, const float* __restrict__ z,
                     const float* __restrict__ W1, const float* __restrict__ b1,
                     const float* __restrict__ W2, const float* __restrict__ b2,
                     const float* __restrict__ W3, const float* __restrict__ b3,
                     float* __restrict__ out) {
  __shared__ __align__(16) __bf16 sm[SMEM_ELTS];
  const int tid = threadIdx.x;
  unsigned* smw = (unsigned*)sm;

  // ---- stage weights transposed + bf16, xor-swizzled 16B chunks ----
  for (int i = tid; i < 4096; i += 256) {           // W1 (64x128)
    int m = i & 127, k = (i >> 7) * 2;
    smw[SW1 / 2 + m * 32 + (((k >> 3) ^ (m & 7)) << 2) + ((k >> 1) & 3)] =
        pkbf(W1[k * 128 + m], W1[(k + 1) * 128 + m]);
  }
  for (int i = tid; i < 8192; i += 256) {           // W2 (128x128)
    int m = i & 127, k = (i >> 7) * 2;
    smw[SW2 / 2 + m * 64 + (((k >> 3) ^ (m & 7)) << 2) + ((k >> 1) & 3)] =
        pkbf(W2[k * 128 + m], W2[(k + 1) * 128 + m]);
  }
  for (int i = tid; i < 768; i += 256) {            // W3 (128x12)
    int kk = i / 12, m = i - kk * 12, k = kk * 2;
    smw[SW3 / 2 + m * 64 + (((k >> 3) ^ (m & 7)) << 2) + ((k >> 1) & 3)] =
        pkbf(W3[k * 12 + m], W3[(k + 1) * 12 + m]);
  }
  if (tid < 128) { sm[SB1 + tid] = (__bf16)b1[tid]; sm[SB2 + tid] = (__bf16)b2[tid]; }
  if (tid < 12)  sm[SB3 + tid] = (__bf16)b3[tid];
  __syncthreads();

  const int wave = tid >> 6;
  const int lane = tid & 63;
  const int q    = lane >> 5;
  const int n    = lane & 31;
  const int s8   = n & 7;
  const int eq   = q ^ (s8 & 1);
  const int sh   = s8 >> 1;

  // per-lane swizzled A-frag base addresses (8 regs; strides are immediates)
  int aw1[4], aw2[4];
  #pragma unroll
  for (int j = 0; j < 4; ++j) {
    aw1[j] = n * 128 + eq * 16 + 32 * (j ^ sh);   // W1: 128 B rows
    aw2[j] = n * 256 + eq * 16 + 32 * (j ^ sh);   // W2/W3: 256 B rows
  }

  // ---- persistent operand fragments, all pinned to the AGPR half ----
  bf16x8 ones;
  #pragma unroll
  for (int i = 0; i < 8; ++i) ones[i] = (__bf16)0.0f;
  if (q == 0) ones[0] = (__bf16)1.0f;
  PIN_AGPR(ones);

  bf16x8 ba1[4], ba2[4], ba3;
  #pragma unroll
  for (int f = 0; f < 4; ++f) {
    ba1[f] = biasA((q == 0) ? sm[SB1 + f * 32 + n] : (__bf16)0.0f);
    ba2[f] = biasA((q == 0) ? sm[SB2 + f * 32 + n] : (__bf16)0.0f);
    PIN_AGPR(ba1[f]); PIN_AGPR(ba2[f]);
  }
  ba3 = biasA((q == 0 && n < 12) ? sm[SB3 + n] : (__bf16)0.0f);
  PIN_AGPR(ba3);

  // persistent zero C-operand (AGPR): every MFMA chain starts from this,
  // eliminating per-tile accumulator zero-init VALU work.
  f32x16 zeroC;
  #pragma unroll
  for (int i = 0; i < 16; ++i) zeroC[i] = 0.0f;
  PIN_AGPR(zeroC);

  const int wid = blockIdx.x * 4 + wave;

  // prefetch z for first tile (single ring slot, 32 regs)
  float4 zv[8];
  {
    const float* zr = z + ((long)wid * 32 + n) * 64;
    #pragma unroll
    for (int kt = 0; kt < 4; ++kt) {
      zv[2 * kt]     = *(const float4*)(zr + kt * 16 + q * 8);
      zv[2 * kt + 1] = *(const float4*)(zr + kt * 16 + q * 8 + 4);
    }
  }

  #pragma unroll 1
  for (int t = wid; t < NTILE; t += WSTRIDE) {
    const long row = (long)t * 32 + n;

    // x for this tile: issued before the z-prefetch so the epilogue's x-wait
    // leaves the prefetch outstanding (R8 behavior).
    const float* xr = x + row * 9;
    float xv0 = xr[q * 4 + 0], xv1 = xr[q * 4 + 1];
    float xv2 = xr[q * 4 + 2], xv3 = xr[q * 4 + 3];
    float xv4 = xr[8];

    // z -> bf16 B-frags (frees the zv ring slot)
    bf16x8 bz[4];
    #pragma unroll
    for (int kt = 0; kt < 4; ++kt) {
      float4 a = zv[2 * kt], b = zv[2 * kt + 1];
      bf16x8 f;
      f[0] = (__bf16)a.x; f[1] = (__bf16)a.y; f[2] = (__bf16)a.z; f[3] = (__bf16)a.w;
      f[4] = (__bf16)b.x; f[5] = (__bf16)b.y; f[6] = (__bf16)b.z; f[7] = (__bf16)b.w;
      bz[kt] = f;
    }

    // EARLY prefetch of next tile's z into the just-freed slot.
    if (t + WSTRIDE < NTILE) {
      const float* zr = z + ((long)(t + WSTRIDE) * 32 + n) * 64;
      #pragma unroll
      for (int kt = 0; kt < 4; ++kt) {
        zv[2 * kt]     = *(const float4*)(zr + kt * 16 + q * 8);
        zv[2 * kt + 1] = *(const float4*)(zr + kt * 16 + q * 8 + 4);
      }
    }

    // ---- layer 1: ft pairs; chains start at bias MFMA (C = zeroC) ----
    bf16x8 bf2[8];
    #pragma unroll
    for (int fp = 0; fp < 2; ++fp) {
      __builtin_amdgcn_s_setprio(1);            // MFMA-dense region begins
      f32x16 aA = MFMA32(ba1[2 * fp + 0], ones, zeroC);
      f32x16 aB = MFMA32(ba1[2 * fp + 1], ones, zeroC);
      PIN_AGPR(aA); PIN_AGPR(aB);
      #pragma unroll
      for (int kt = 0; kt < 4; ++kt) {
        aA = MFMA32(ldw(sm, aw1[kt], SW1 * 2 + (2 * fp + 0) * 4096), bz[kt], aA);
        aB = MFMA32(ldw(sm, aw1[kt], SW1 * 2 + (2 * fp + 1) * 4096), bz[kt], aB);
      }
      __builtin_amdgcn_s_setprio(0);            // VALU pack phase: yield
      #pragma unroll
      for (int i = 0; i < 16; ++i) { aA[i] = fmaxf(aA[i], 0.0f); aB[i] = fmaxf(aB[i], 0.0f); }
      bf2[4 * fp + 0] = mk_bfrag<0>(aA);
      bf2[4 * fp + 1] = mk_bfrag<1>(aA);
      bf2[4 * fp + 2] = mk_bfrag<0>(aB);
      bf2[4 * fp + 3] = mk_bfrag<1>(aB);
    }

    // ---- layer 2 (bias-start chains) with layer 3 fused ----
    f32x16 acc3 = MFMA32(ba3, ones, zeroC);
    PIN_AGPR(acc3);
    #pragma unroll
    for (int fp = 0; fp < 2; ++fp) {
      __builtin_amdgcn_s_setprio(1);            // MFMA-dense region begins
      f32x16 aA = MFMA32(ba2[2 * fp + 0], ones, zeroC);
      f32x16 aB = MFMA32(ba2[2 * fp + 1], ones, zeroC);
      PIN_AGPR(aA); PIN_AGPR(aB);
      #pragma unroll
      for (int kt = 0; kt < 8; ++kt) {
        aA = MFMA32(ldw(sm, aw2[kt & 3], SW2 * 2 + (2 * fp + 0) * 8192 + 128 * (kt >> 2)),
                    bf2[kt], aA);
        aB = MFMA32(ldw(sm, aw2[kt & 3], SW2 * 2 + (2 * fp + 1) * 8192 + 128 * (kt >> 2)),
                    bf2[kt], aB);
      }
      __builtin_amdgcn_s_setprio(0);            // VALU relu/pack: yield
      #pragma unroll
      for (int i = 0; i < 16; ++i) { aA[i] = fmaxf(aA[i], 0.0f); aB[i] = fmaxf(aB[i], 0.0f); }
      // h2 features 64*fp + [0,64) == layer-3 K block kt = 4*fp + [0,4)
      bf16x8 p0 = mk_bfrag<0>(aA), p1 = mk_bfrag<1>(aA);
      bf16x8 p2 = mk_bfrag<0>(aB), p3 = mk_bfrag<1>(aB);
      __builtin_amdgcn_s_setprio(1);            // L3 MFMA tail
      acc3 = MFMA32(ldw(sm, aw2[0], SW3 * 2 + 128 * fp), p0, acc3);
      acc3 = MFMA32(ldw(sm, aw2[1], SW3 * 2 + 128 * fp), p1, acc3);
      acc3 = MFMA32(ldw(sm, aw2[2], SW3 * 2 + 128 * fp), p2, acc3);
      acc3 = MFMA32(ldw(sm, aw2[3], SW3 * 2 + 128 * fp), p3, acc3);
      __builtin_amdgcn_s_setprio(0);            // epilogue/next-phase: yield
    }

    // ---- epilogue (only regs 0..7 carry real features) ----
    float t0 = acc3[0], t1 = acc3[1], t2 = acc3[2], t3 = acc3[3];
    float t4 = acc3[4], t5 = acc3[5], t6 = acc3[6], t7 = acc3[7];
    float o0 = 0.f, o1 = 0.f, o2 = 0.f, g1v = 0.f, g2v = 0.f;
    if (q == 0) {
      t0 = fminf(t0, 0.0f); t1 = fminf(t1, 0.0f);
      t2 = fminf(t2, 0.0f); t3 = fminf(t3, 0.0f);
      t4 = fminf(t4, 0.0f);                       // feat 8
      o0 = xv0 * t0 + xv1 * t1 + xv2 * t2 + t5;   // seg0 + I9
      o1 = xv3 * t3 + t6;                         // seg1 part + I10
      o2 = xv4 * t4 + t7;                         // seg2 part + I11
    } else {
      t0 = fminf(t0, 0.0f); t1 = fminf(t1, 0.0f); // feats 4,5
      t3 = fminf(t3, 0.0f);                       // feat 7 (feat 6 passes)
      g1v = xv0 * t0 + xv1 * t1;
      g2v = xv2 * t2 + xv3 * t3;
    }
    float a1v = __shfl_xor(g1v, 32, 64);
    float a2v = __shfl_xor(g2v, 32, 64);
    if (q == 0) {
      float* op = out + row * 3;
      op[0] = o0;
      op[1] = o1 + a1v;
      op[2] = o2 + a2v;
    }
  }
}

extern "C" void kernel_launch(void* const* d_in, const int* in_sizes, int n_in,
                              void* d_out, int out_size, void* d_ws, size_t ws_size,
                              hipStream_t stream) {
  const float* x  = (const float*)d_in[0];
  const float* z  = (const float*)d_in[1];
  const float* W1 = (const float*)d_in[2];
  const float* b1 = (const float*)d_in[3];
  const float* W2 = (const float*)d_in[4];
  const float* b2 = (const float*)d_in[5];
  const float* W3 = (const float*)d_in[6];
  const float* b3 = (const float*)d_in[7];
  tastenet_kernel<<<dim3(NBLK), dim3(256), 0, stream>>>(
      x, z, W1, b1, W2, b2, W3, b3, (float*)d_out);
}

// Round 14
// 234.400 us; speedup vs baseline: 3.5119x; 1.0073x over previous
//
#include <hip/hip_runtime.h>
#include <hip/hip_bf16.h>

// TasteNet fused MLP: z(N,64) -> h1(128) relu -> h2(128) relu -> b(12) ->
// clamp/taste/segment-sum epilogue with x(N,9) -> out(N,3) fp32.
//
// R24 = R23 resubmitted verbatim (R23 bench was a GPUAcquisitionTimeout).
// R23 = R10 VERBATIM — final revert per R22's decision rule.
// R22 measured setprio at 84.4-85.7 us vs R10's 83.4 (neutral-to-negative;
// the prioritized MFMA wave is dependency-stalled and can't use the issue
// slots it wins). Stripped. R22 also proved R10's residual 2MB spill is
// harmless (spill-free variant was SLOWER), closing the last open sub-theory.
//
// Session summary (12 measured rounds): R10 is a sharp local optimum.
//   R11  3 waves/SIMD        -> arch/AGPR split spill, 130 us (+56%)
//   R13  4-way MFMA ILP      -> spill, 97 us (+16%)
//   R17  z-ring via LDS      -> +LDS round-trip latency, 89.5 us (+7%)
//   R18  weights-in-AGPR     -> catastrophic spill, 695 us (+730%)
//   R22  setprio (T5)        -> 85.5 us (+2.5%)
// Constraint is structural: latency-bound dependent ds_read_b128->MFMA
// chains (64/tile, 56 loop-invariant) that can only be shortened with more
// per-wave state, against a 256-reg/wave file already at the cliff. Not a
// HW roofline (MfmaUtil 16%, HBM 13%) — a measured local minimum with
// positive gradient in every feasible direction.
//
// Structure: z-prefetch ring in regs (32), AGPR-pinned biases + ones +
// zeroC (R8 win: no per-chain acc zero-init), bias-start MFMA chains,
// permlane32_swap frag conversion, fused L3 + clamp/taste/segment epilogue.
// Grid 512 x (256,2), 2 waves/SIMD.

typedef __bf16 bf16x8 __attribute__((ext_vector_type(8)));
typedef float  f32x16 __attribute__((ext_vector_type(16)));
typedef unsigned int uint2v __attribute__((ext_vector_type(2)));
typedef unsigned int uint4v __attribute__((ext_vector_type(4)));

#define MFMA32(a, b, c) __builtin_amdgcn_mfma_f32_32x32x16_bf16((a), (b), (c), 0, 0, 0)
// Pin a value into the AGPR half of the unified file (R8 win).
#define PIN_AGPR(v) asm("" : "+a"(v))

// ---- LDS layout (bf16 element offsets), verified R2-R22 ----
#define SW3 0        // 12 rows x 128 elts (row reads m=12..31 overrun into SW1;
                     // garbage feats land in acc3 regs never read)
#define SW1 1536     // 128 rows x 64 elts (128 B row, xor-swizzled 16B chunks)
#define SW2 9728     // 128 rows x 128 elts (256 B row, swizzled)
#define SB1 26112
#define SB2 26240
#define SB3 26368
#define SMEM_ELTS 26384   // 52768 B

#define NBLK    512
#define NTILE   16384          // 524288 rows / 32
#define WSTRIDE (NBLK * 4)     // 2048 waves -> exactly 8 tiles each

__device__ __forceinline__ unsigned pkbf(float lo, float hi) {
  unsigned short lb = __builtin_bit_cast(unsigned short, (__bf16)lo);
  unsigned short hb = __builtin_bit_cast(unsigned short, (__bf16)hi);
  return ((unsigned)hb << 16) | (unsigned)lb;
}

// 32x32 C-layout -> next-layer B-frag via one permlane32_swap per packed pair.
// Verified R1-R22 (absmax 5.9e-3).
template <int SUB>
__device__ __forceinline__ bf16x8 mk_bfrag(const f32x16 h) {
  constexpr int B = SUB * 8;
  unsigned p01 = pkbf(h[B + 0], h[B + 1]);
  unsigned p23 = pkbf(h[B + 2], h[B + 3]);
  unsigned p45 = pkbf(h[B + 4], h[B + 5]);
  unsigned p67 = pkbf(h[B + 6], h[B + 7]);
  unsigned d0, d1, d2, d3;
#if __has_builtin(__builtin_amdgcn_permlane32_swap)
  uint2v r1 = __builtin_amdgcn_permlane32_swap(p01, p45, false, false);
  uint2v r2 = __builtin_amdgcn_permlane32_swap(p23, p67, false, false);
  d0 = r1[0]; d2 = r1[1];
  d1 = r2[0]; d3 = r2[1];
#else
  int hi = (threadIdx.x >> 5) & 1;
  unsigned sp01 = (unsigned)__shfl_xor((int)p01, 32, 64);
  unsigned sp23 = (unsigned)__shfl_xor((int)p23, 32, 64);
  unsigned sp45 = (unsigned)__shfl_xor((int)p45, 32, 64);
  unsigned sp67 = (unsigned)__shfl_xor((int)p67, 32, 64);
  d0 = hi ? sp45 : p01;
  d2 = hi ? p45  : sp01;
  d1 = hi ? sp67 : p23;
  d3 = hi ? p67  : sp23;
#endif
  uint4v t; t[0] = d0; t[1] = d1; t[2] = d2; t[3] = d3;
  return __builtin_bit_cast(bf16x8, t);
}

// LDS A-frag read: VGPR addr + compile-time immediate byte offset.
__device__ __forceinline__ bf16x8 ldw(const __bf16* sm, int vaddr, int imm) {
  return *(const bf16x8*)((const char*)sm + vaddr + imm);
}

// bias A-frag: A[m][0] = v on q=0 lanes; MFMA'd against ones-B (B[0][:]=1)
__device__ __forceinline__ bf16x8 biasA(__bf16 v) {
  bf16x8 f;
  #pragma unroll
  for (int i = 0; i < 8; ++i) f[i] = (__bf16)0.0f;
  f[0] = v;
  return f;
}

__global__ __launch_bounds__(256, 2)
void tastenet_kernel(const float* __restrict__ x, const float* __restrict__ z,
                     const float* __restrict__ W1, const float* __restrict__ b1,
                     const float* __restrict__ W2, const float* __restrict__ b2,
                     const float* __restrict__ W3, const float* __restrict__ b3,
                     float* __restrict__ out) {
  __shared__ __align__(16) __bf16 sm[SMEM_ELTS];
  const int tid = threadIdx.x;
  unsigned* smw = (unsigned*)sm;

  // ---- stage weights transposed + bf16, xor-swizzled 16B chunks ----
  for (int i = tid; i < 4096; i += 256) {           // W1 (64x128)
    int m = i & 127, k = (i >> 7) * 2;
    smw[SW1 / 2 + m * 32 + (((k >> 3) ^ (m & 7)) << 2) + ((k >> 1) & 3)] =
        pkbf(W1[k * 128 + m], W1[(k + 1) * 128 + m]);
  }
  for (int i = tid; i < 8192; i += 256) {           // W2 (128x128)
    int m = i & 127, k = (i >> 7) * 2;
    smw[SW2 / 2 + m * 64 + (((k >> 3) ^ (m & 7)) << 2) + ((k >> 1) & 3)] =
        pkbf(W2[k * 128 + m], W2[(k + 1) * 128 + m]);
  }
  for (int i = tid; i < 768; i += 256) {            // W3 (128x12)
    int kk = i / 12, m = i - kk * 12, k = kk * 2;
    smw[SW3 / 2 + m * 64 + (((k >> 3) ^ (m & 7)) << 2) + ((k >> 1) & 3)] =
        pkbf(W3[k * 12 + m], W3[(k + 1) * 12 + m]);
  }
  if (tid < 128) { sm[SB1 + tid] = (__bf16)b1[tid]; sm[SB2 + tid] = (__bf16)b2[tid]; }
  if (tid < 12)  sm[SB3 + tid] = (__bf16)b3[tid];
  __syncthreads();

  const int wave = tid >> 6;
  const int lane = tid & 63;
  const int q    = lane >> 5;
  const int n    = lane & 31;
  const int s8   = n & 7;
  const int eq   = q ^ (s8 & 1);
  const int sh   = s8 >> 1;

  // per-lane swizzled A-frag base addresses (8 regs; strides are immediates)
  int aw1[4], aw2[4];
  #pragma unroll
  for (int j = 0; j < 4; ++j) {
    aw1[j] = n * 128 + eq * 16 + 32 * (j ^ sh);   // W1: 128 B rows
    aw2[j] = n * 256 + eq * 16 + 32 * (j ^ sh);   // W2/W3: 256 B rows
  }

  // ---- persistent operand fragments, all pinned to the AGPR half ----
  bf16x8 ones;
  #pragma unroll
  for (int i = 0; i < 8; ++i) ones[i] = (__bf16)0.0f;
  if (q == 0) ones[0] = (__bf16)1.0f;
  PIN_AGPR(ones);

  bf16x8 ba1[4], ba2[4], ba3;
  #pragma unroll
  for (int f = 0; f < 4; ++f) {
    ba1[f] = biasA((q == 0) ? sm[SB1 + f * 32 + n] : (__bf16)0.0f);
    ba2[f] = biasA((q == 0) ? sm[SB2 + f * 32 + n] : (__bf16)0.0f);
    PIN_AGPR(ba1[f]); PIN_AGPR(ba2[f]);
  }
  ba3 = biasA((q == 0 && n < 12) ? sm[SB3 + n] : (__bf16)0.0f);
  PIN_AGPR(ba3);

  // persistent zero C-operand (AGPR): every MFMA chain starts from this,
  // eliminating per-tile accumulator zero-init VALU work.
  f32x16 zeroC;
  #pragma unroll
  for (int i = 0; i < 16; ++i) zeroC[i] = 0.0f;
  PIN_AGPR(zeroC);

  const int wid = blockIdx.x * 4 + wave;

  // prefetch z for first tile (single ring slot, 32 regs)
  float4 zv[8];
  {
    const float* zr = z + ((long)wid * 32 + n) * 64;
    #pragma unroll
    for (int kt = 0; kt < 4; ++kt) {
      zv[2 * kt]     = *(const float4*)(zr + kt * 16 + q * 8);
      zv[2 * kt + 1] = *(const float4*)(zr + kt * 16 + q * 8 + 4);
    }
  }

  #pragma unroll 1
  for (int t = wid; t < NTILE; t += WSTRIDE) {
    const long row = (long)t * 32 + n;

    // x for this tile: issued before the z-prefetch so the epilogue's x-wait
    // leaves the prefetch outstanding (R8 behavior).
    const float* xr = x + row * 9;
    float xv0 = xr[q * 4 + 0], xv1 = xr[q * 4 + 1];
    float xv2 = xr[q * 4 + 2], xv3 = xr[q * 4 + 3];
    float xv4 = xr[8];

    // z -> bf16 B-frags (frees the zv ring slot)
    bf16x8 bz[4];
    #pragma unroll
    for (int kt = 0; kt < 4; ++kt) {
      float4 a = zv[2 * kt], b = zv[2 * kt + 1];
      bf16x8 f;
      f[0] = (__bf16)a.x; f[1] = (__bf16)a.y; f[2] = (__bf16)a.z; f[3] = (__bf16)a.w;
      f[4] = (__bf16)b.x; f[5] = (__bf16)b.y; f[6] = (__bf16)b.z; f[7] = (__bf16)b.w;
      bz[kt] = f;
    }

    // EARLY prefetch of next tile's z into the just-freed slot.
    if (t + WSTRIDE < NTILE) {
      const float* zr = z + ((long)(t + WSTRIDE) * 32 + n) * 64;
      #pragma unroll
      for (int kt = 0; kt < 4; ++kt) {
        zv[2 * kt]     = *(const float4*)(zr + kt * 16 + q * 8);
        zv[2 * kt + 1] = *(const float4*)(zr + kt * 16 + q * 8 + 4);
      }
    }

    // ---- layer 1: ft pairs; chains start at bias MFMA (C = zeroC) ----
    bf16x8 bf2[8];
    #pragma unroll
    for (int fp = 0; fp < 2; ++fp) {
      f32x16 aA = MFMA32(ba1[2 * fp + 0], ones, zeroC);
      f32x16 aB = MFMA32(ba1[2 * fp + 1], ones, zeroC);
      PIN_AGPR(aA); PIN_AGPR(aB);
      #pragma unroll
      for (int kt = 0; kt < 4; ++kt) {
        aA = MFMA32(ldw(sm, aw1[kt], SW1 * 2 + (2 * fp + 0) * 4096), bz[kt], aA);
        aB = MFMA32(ldw(sm, aw1[kt], SW1 * 2 + (2 * fp + 1) * 4096), bz[kt], aB);
      }
      #pragma unroll
      for (int i = 0; i < 16; ++i) { aA[i] = fmaxf(aA[i], 0.0f); aB[i] = fmaxf(aB[i], 0.0f); }
      bf2[4 * fp + 0] = mk_bfrag<0>(aA);
      bf2[4 * fp + 1] = mk_bfrag<1>(aA);
      bf2[4 * fp + 2] = mk_bfrag<0>(aB);
      bf2[4 * fp + 3] = mk_bfrag<1>(aB);
    }

    // ---- layer 2 (bias-start chains) with layer 3 fused ----
    f32x16 acc3 = MFMA32(ba3, ones, zeroC);
    PIN_AGPR(acc3);
    #pragma unroll
    for (int fp = 0; fp < 2; ++fp) {
      f32x16 aA = MFMA32(ba2[2 * fp + 0], ones, zeroC);
      f32x16 aB = MFMA32(ba2[2 * fp + 1], ones, zeroC);
      PIN_AGPR(aA); PIN_AGPR(aB);
      #pragma unroll
      for (int kt = 0; kt < 8; ++kt) {
        aA = MFMA32(ldw(sm, aw2[kt & 3], SW2 * 2 + (2 * fp + 0) * 8192 + 128 * (kt >> 2)),
                    bf2[kt], aA);
        aB = MFMA32(ldw(sm, aw2[kt & 3], SW2 * 2 + (2 * fp + 1) * 8192 + 128 * (kt >> 2)),
                    bf2[kt], aB);
      }
      #pragma unroll
      for (int i = 0; i < 16; ++i) { aA[i] = fmaxf(aA[i], 0.0f); aB[i] = fmaxf(aB[i], 0.0f); }
      // h2 features 64*fp + [0,64) == layer-3 K block kt = 4*fp + [0,4)
      acc3 = MFMA32(ldw(sm, aw2[0], SW3 * 2 + 128 * fp), mk_bfrag<0>(aA), acc3);
      acc3 = MFMA32(ldw(sm, aw2[1], SW3 * 2 + 128 * fp), mk_bfrag<1>(aA), acc3);
      acc3 = MFMA32(ldw(sm, aw2[2], SW3 * 2 + 128 * fp), mk_bfrag<0>(aB), acc3);
      acc3 = MFMA32(ldw(sm, aw2[3], SW3 * 2 + 128 * fp), mk_bfrag<1>(aB), acc3);
    }

    // ---- epilogue (only regs 0..7 carry real features) ----
    float t0 = acc3[0], t1 = acc3[1], t2 = acc3[2], t3 = acc3[3];
    float t4 = acc3[4], t5 = acc3[5], t6 = acc3[6], t7 = acc3[7];
    float o0 = 0.f, o1 = 0.f, o2 = 0.f, g1v = 0.f, g2v = 0.f;
    if (q == 0) {
      t0 = fminf(t0, 0.0f); t1 = fminf(t1, 0.0f);
      t2 = fminf(t2, 0.0f); t3 = fminf(t3, 0.0f);
      t4 = fminf(t4, 0.0f);                       // feat 8
      o0 = xv0 * t0 + xv1 * t1 + xv2 * t2 + t5;   // seg0 + I9
      o1 = xv3 * t3 + t6;                         // seg1 part + I10
      o2 = xv4 * t4 + t7;                         // seg2 part + I11
    } else {
      t0 = fminf(t0, 0.0f); t1 = fminf(t1, 0.0f); // feats 4,5
      t3 = fminf(t3, 0.0f);                       // feat 7 (feat 6 passes)
      g1v = xv0 * t0 + xv1 * t1;
      g2v = xv2 * t2 + xv3 * t3;
    }
    float a1v = __shfl_xor(g1v, 32, 64);
    float a2v = __shfl_xor(g2v, 32, 64);
    if (q == 0) {
      float* op = out + row * 3;
      op[0] = o0;
      op[1] = o1 + a1v;
      op[2] = o2 + a2v;
    }
  }
}

extern "C" void kernel_launch(void* const* d_in, const int* in_sizes, int n_in,
                              void* d_out, int out_size, void* d_ws, size_t ws_size,
                              hipStream_t stream) {
  const float* x  = (const float*)d_in[0];
  const float* z  = (const float*)d_in[1];
  const float* W1 = (const float*)d_in[2];
  const float* b1 = (const float*)d_in[3];
  const float* W2 = (const float*)d_in[4];
  const float* b2 = (const float*)d_in[5];
  const float* W3 = (const float*)d_in[6];
  const float* b3 = (const float*)d_in[7];
  tastenet_kernel<<<dim3(NBLK), dim3(256), 0, stream>>>(
      x, z, W1, b1, W2, b2, W3, b3, (float*)d_out);
}